// Round 1
// baseline (603.162 us; speedup 1.0000x reference)
//
#include <hip/hip_runtime.h>
#include <cstdint>

#define MUL0 16
#define MUL1 8
#define NRBF 8
#define HID 64
#define WNUM 576
#define CUTOFF 5.0f
#define EPSF 1e-8f

#define INV_SQRT3 0.57735026918962576f
#define A_PATH    0.20412414523193154f   /* 1/sqrt(24) */
#define Q16       0.25f                  /* 1/sqrt(16) */
#define Q8        0.35355339059327373f   /* 1/sqrt(8)  */
#define PI_OVER_CUT 0.62831853071795865f /* pi/5 */

typedef _Float16 f16;
typedef _Float16 f16x8 __attribute__((ext_vector_type(8)));
typedef float f32x4 __attribute__((ext_vector_type(4)));

__device__ __forceinline__ float sigm(float x) { return 1.0f / (1.0f + __expf(-x)); }

// compiler-level ordering fence for intra-wave LDS RAW (no runtime cost;
// same-wave DS ops execute in order at the LDS pipe)
__device__ __forceinline__ void wavefence() {
  asm volatile("" ::: "memory");
  __builtin_amdgcn_wave_barrier();
  asm volatile("" ::: "memory");
}

// ---------------- prep: w_r2 (64 x 576 f32) -> W2T (576 x 64 f16) ----------------
extern "C" __global__ __launch_bounds__(256) void k_prep_w2t(
    const float* __restrict__ w_r2, f16* __restrict__ W2T) {
  int t = blockIdx.x * 256 + threadIdx.x;
  if (t >= HID * WNUM) return;
  int n = t >> 6, k = t & 63;
  W2T[n * 64 + k] = (f16)w_r2[k * WNUM + n];
}

// ---------------- node irrep norm (vectorized) ----------------
extern "C" __global__ __launch_bounds__(256) void k_xnorm(
    const float* __restrict__ x, float* __restrict__ xnorm, int N) {
  int n = blockIdx.x * 256 + threadIdx.x;
  if (n >= N) return;
  const float4* xr = (const float4*)(x + (long long)n * 40);
  float4 vv[10];
#pragma unroll
  for (int i = 0; i < 10; i++) vv[i] = xr[i];
  float* f = (float*)vv;
  float ss = 0.f, vs = 0.f;
#pragma unroll
  for (int i = 0; i < 16; i++) ss += f[i] * f[i];
#pragma unroll
  for (int i = 16; i < 40; i++) vs += f[i] * f[i];
  float sr = rsqrtf(ss * (1.0f / 16.0f) + EPSF);
  float vr = rsqrtf(vs * (1.0f / 8.0f) + EPSF);
#pragma unroll
  for (int i = 0; i < 16; i++) f[i] *= sr;
#pragma unroll
  for (int i = 16; i < 40; i++) f[i] *= vr;
  float4* o = (float4*)(xnorm + (long long)n * 40);
#pragma unroll
  for (int i = 0; i < 10; i++) o[i] = vv[i];
}

// ---------------- fused edge kernel: barrier-free, wave-local ----------------
// block = 256 threads = 4 independent waves; each wave owns 16 edges.
extern "C" __global__ __launch_bounds__(256, 4) void k_edge(
    const float* __restrict__ xnorm, const int* __restrict__ esrc,
    const int* __restrict__ edst, const float* __restrict__ sh,
    const float* __restrict__ rbf, const float* __restrict__ elen,
    const float* __restrict__ w_r1, const float* __restrict__ b_r1,
    const float* __restrict__ w_g1, const float* __restrict__ b_g1,
    const float* __restrict__ w_g2, const float* __restrict__ b_g2,
    const float* __restrict__ b_r2, const f16* __restrict__ W2T,
    float* __restrict__ agg0, float* __restrict__ agg1,
    float* __restrict__ normb, int E) {
  // strides padded so the 4 quads' rows land on distinct/2-way banks
  __shared__ __align__(16) f16   s_H[4][16][72];    // H, row = edge
  __shared__ __align__(16) float s_sn[4][16][20];   // raw normalized scalars
  __shared__ __align__(16) float s_v[4][16][28];    // raw normalized vectors (24 used)
  __shared__ __align__(16) float s_a1[4][16][12];   // INV_SQRT3 * (v . sh1), 8 used
  __shared__ __align__(16) float s_sh[4][16][4];
  __shared__ __align__(16) float s_rbf[4][16][8];
  __shared__ float s_ew[4][16];
  __shared__ int   s_dst[4][16];

  const int t = threadIdx.x;
  const int w = t >> 6;
  const int lane = t & 63;
  const long long eb = (long long)blockIdx.x * 64 + w * 16;  // wave's first edge

  // ---- A0: independent global loads + wave-local staging ----
  const int ge_l = lane >> 2;       // local edge for gather (0..15)
  const int part = lane & 3;        // which chunk of the 40-float row
  const long long ge = eb + ge_l;
  int srcn = 0;
  float4 shv = {0.f, 0.f, 0.f, 0.f};
  if (ge < E) {
    srcn = esrc[ge];
    shv = *(const float4*)&sh[ge * 4];
  }
  {
    long long gb = eb * 8 + lane;
    float r0 = (gb < (long long)E * 8) ? rbf[gb] : 0.f;
    float r1 = (gb + 64 < (long long)E * 8) ? rbf[gb + 64] : 0.f;
    (&s_rbf[w][0][0])[lane] = r0;
    (&s_rbf[w][0][0])[lane + 64] = r1;
    long long gs = eb * 4 + lane;
    (&s_sh[w][0][0])[lane] = (gs < (long long)E * 4) ? sh[gs] : 0.f;
    if (lane < 16) {
      long long g2 = eb + lane;
      s_dst[w][lane] = (g2 < E) ? edst[g2] : 0;
    }
  }
  wavefence();

  // ---- A1: gather + transform (4 lanes per edge, float4 loads) ----
  {
    const float* xr = xnorm + (long long)srcn * 40;
    if (part < 2) {
      float4 aLo = *(const float4*)(xr + part * 8);
      float4 aHi = *(const float4*)(xr + part * 8 + 4);
      *(float4*)&s_sn[w][ge_l][part * 8] = aLo;
      *(float4*)&s_sn[w][ge_l][part * 8 + 4] = aHi;
    } else {
      const int i0 = (part - 2) * 4;  // 0 or 4
      const float* vp = xr + 16 + i0 * 3;
      float4 v0 = *(const float4*)(vp);
      float4 v1 = *(const float4*)(vp + 4);
      float4 v2 = *(const float4*)(vp + 8);
      *(float4*)&s_v[w][ge_l][i0 * 3] = v0;
      *(float4*)&s_v[w][ge_l][i0 * 3 + 4] = v1;
      *(float4*)&s_v[w][ge_l][i0 * 3 + 8] = v2;
      float s1x = shv.y, s1y = shv.z, s1z = shv.w;
      s_a1[w][ge_l][i0]     = INV_SQRT3 * (v0.x * s1x + v0.y * s1y + v0.z * s1z);
      s_a1[w][ge_l][i0 + 1] = INV_SQRT3 * (v0.w * s1x + v1.x * s1y + v1.y * s1z);
      s_a1[w][ge_l][i0 + 2] = INV_SQRT3 * (v1.z * s1x + v1.w * s1y + v2.x * s1z);
      s_a1[w][ge_l][i0 + 3] = INV_SQRT3 * (v2.y * s1x + v2.z * s1y + v2.w * s1z);
    }
  }

  // ---- A2: hidden layer H (f16), lane = h, 16 edges of this wave ----
  {
    float wr[8];
#pragma unroll
    for (int r = 0; r < 8; r++) wr[r] = w_r1[r * HID + lane];
    float bh = b_r1[lane];
#pragma unroll
    for (int u = 0; u < 16; u++) {
      float4 ra = *(const float4*)&s_rbf[w][u][0];
      float4 rb = *(const float4*)&s_rbf[w][u][4];
      float acc = bh + ra.x * wr[0] + ra.y * wr[1] + ra.z * wr[2] + ra.w * wr[3]
                     + rb.x * wr[4] + rb.y * wr[5] + rb.z * wr[6] + rb.w * wr[7];
      s_H[w][u][lane] = (f16)(acc * sigm(acc));
    }
  }

  // ---- A3: gate MLP, all 64 lanes (16 h-units per lane) + shfl reduce ----
  {
    const int eg = lane & 15;
    const int grp = lane >> 4;
    float4 ga = *(const float4*)&s_rbf[w][eg][0];
    float4 gb = *(const float4*)&s_rbf[w][eg][4];
    float rv[8] = {ga.x, ga.y, ga.z, ga.w, gb.x, gb.y, gb.z, gb.w};
    float tt[16];
    {
      const float4 b0 = *(const float4*)&b_g1[grp * 16];
      const float4 b1 = *(const float4*)&b_g1[grp * 16 + 4];
      const float4 b2 = *(const float4*)&b_g1[grp * 16 + 8];
      const float4 b3 = *(const float4*)&b_g1[grp * 16 + 12];
      tt[0] = b0.x; tt[1] = b0.y; tt[2] = b0.z; tt[3] = b0.w;
      tt[4] = b1.x; tt[5] = b1.y; tt[6] = b1.z; tt[7] = b1.w;
      tt[8] = b2.x; tt[9] = b2.y; tt[10] = b2.z; tt[11] = b2.w;
      tt[12] = b3.x; tt[13] = b3.y; tt[14] = b3.z; tt[15] = b3.w;
    }
#pragma unroll
    for (int r = 0; r < 8; r++) {
      const float* wg = w_g1 + r * HID + grp * 16;
      float4 w0 = *(const float4*)(wg);
      float4 w1 = *(const float4*)(wg + 4);
      float4 w2 = *(const float4*)(wg + 8);
      float4 w3 = *(const float4*)(wg + 12);
      float rr = rv[r];
      tt[0] += rr * w0.x; tt[1] += rr * w0.y; tt[2] += rr * w0.z; tt[3] += rr * w0.w;
      tt[4] += rr * w1.x; tt[5] += rr * w1.y; tt[6] += rr * w1.z; tt[7] += rr * w1.w;
      tt[8] += rr * w2.x; tt[9] += rr * w2.y; tt[10] += rr * w2.z; tt[11] += rr * w2.w;
      tt[12] += rr * w3.x; tt[13] += rr * w3.y; tt[14] += rr * w3.z; tt[15] += rr * w3.w;
    }
    float gw[16];
    {
      const float4 g0 = *(const float4*)&w_g2[grp * 16];
      const float4 g1 = *(const float4*)&w_g2[grp * 16 + 4];
      const float4 g2 = *(const float4*)&w_g2[grp * 16 + 8];
      const float4 g3 = *(const float4*)&w_g2[grp * 16 + 12];
      gw[0] = g0.x; gw[1] = g0.y; gw[2] = g0.z; gw[3] = g0.w;
      gw[4] = g1.x; gw[5] = g1.y; gw[6] = g1.z; gw[7] = g1.w;
      gw[8] = g2.x; gw[9] = g2.y; gw[10] = g2.z; gw[11] = g2.w;
      gw[12] = g3.x; gw[13] = g3.y; gw[14] = g3.z; gw[15] = g3.w;
    }
    float accp = 0.f;
#pragma unroll
    for (int k = 0; k < 16; k++) accp += tt[k] * sigm(tt[k]) * gw[k];
    accp += __shfl_xor(accp, 16);
    accp += __shfl_xor(accp, 32);
    if (lane < 16) {
      long long g2e = eb + lane;
      float ew = 0.f;
      if (g2e < E) {
        float len = elen[g2e];
        float cw = (len < CUTOFF) ? 0.5f * (__cosf(PI_OVER_CUT * len) + 1.0f) : 0.f;
        ew = cw * sigm(accp + b_g2[0]);
      }
      s_ew[w][lane] = ew;
    }
  }
  wavefence();

  // ---- B: MFMA over 36 j-tiles, fully unrolled so loads pipeline ----
  const int quad = lane >> 4;
  const int c = lane & 15;

  const f16x8 af0 = *(const f16x8*)&s_H[w][c][quad * 8];
  const f16x8 af1 = *(const f16x8*)&s_H[w][c][32 + quad * 8];

  float p1[4] = {0.f, 0.f, 0.f, 0.f};   // w1 path (x sh0 at epilogue)
  float p2[4] = {0.f, 0.f, 0.f, 0.f};   // w2 path
  float t3[4] = {0.f, 0.f, 0.f, 0.f};   // w3 path (x sh1 at epilogue)
  float mx[4] = {0.f, 0.f, 0.f, 0.f};   // w4 path (x sh0 at epilogue)
  float my[4] = {0.f, 0.f, 0.f, 0.f};
  float mz[4] = {0.f, 0.f, 0.f, 0.f};

  const f16* wb = W2T + (long long)c * 64 + quad * 8;
  const float* bp = b_r2 + c;

#pragma unroll
  for (int jt = 0; jt < 36; jt++) {
    const f16* nb = wb + jt * 1024;
    f16x8 b0 = *(const f16x8*)(nb);
    f16x8 b1 = *(const f16x8*)(nb + 32);
    float bias = bp[jt * 16];
    f32x4 C = {0.f, 0.f, 0.f, 0.f};
    C = __builtin_amdgcn_mfma_f32_16x16x32_f16(af0, b0, C, 0, 0, 0);
    C = __builtin_amdgcn_mfma_f32_16x16x32_f16(af1, b1, C, 0, 0, 0);
    if (jt < 16) {
#pragma unroll
      for (int r = 0; r < 4; r++)
        p1[r] += s_sn[w][quad * 4 + r][jt] * (C[r] + bias);
    } else if (jt < 24) {
      const int i = jt - 16;
#pragma unroll
      for (int r = 0; r < 4; r++)
        p2[r] += s_a1[w][quad * 4 + r][i] * (C[r] + bias);
    } else if (jt < 32) {
      const int i = (jt - 24) * 2 + (c >> 3);
#pragma unroll
      for (int r = 0; r < 4; r++)
        t3[r] += s_sn[w][quad * 4 + r][i] * (C[r] + bias);
    } else {
      const int i = (jt - 32) * 2 + (c >> 3);
#pragma unroll
      for (int r = 0; r < 4; r++) {
        float wvv = C[r] + bias;
        mx[r] += s_v[w][quad * 4 + r][3 * i] * wvv;
        my[r] += s_v[w][quad * 4 + r][3 * i + 1] * wvv;
        mz[r] += s_v[w][quad * 4 + r][3 * i + 2] * wvv;
      }
    }
  }

  // fold the two column-halves (c and c^8 share output j = c&7)
#pragma unroll
  for (int r = 0; r < 4; r++) {
    t3[r] += __shfl_xor(t3[r], 8);
    mx[r] += __shfl_xor(mx[r], 8);
    my[r] += __shfl_xor(my[r], 8);
    mz[r] += __shfl_xor(mz[r], 8);
  }

  // ---- epilogue: scale + atomic scatter ----
#pragma unroll
  for (int r = 0; r < 4; r++) {
    const int e = quad * 4 + r;
    float ew = s_ew[w][e];
    float sc = A_PATH * ew;
    int dst = s_dst[w][e];
    float sh0 = s_sh[w][e][0];
    atomicAdd(&agg0[(long long)dst * 16 + c], (sh0 * p1[r] + p2[r]) * sc);
    if (c < 8) {
      float t3v = t3[r] * sc;
      float scs = sc * sh0;
      float ox = t3v * s_sh[w][e][1] + mx[r] * scs;
      float oy = t3v * s_sh[w][e][2] + my[r] * scs;
      float oz = t3v * s_sh[w][e][3] + mz[r] * scs;
      long long b = (long long)dst * 24 + (long long)c * 3;
      atomicAdd(&agg1[b], ox);
      atomicAdd(&agg1[b + 1], oy);
      atomicAdd(&agg1[b + 2], oz);
    } else if (c == 8) {
      atomicAdd(&normb[dst], ew);
    }
  }
}

// ---------------- final node kernel (vectorized loads/stores) ----------------
extern "C" __global__ __launch_bounds__(256) void k_node(
    const float* __restrict__ x, const float* __restrict__ xnorm,
    const float* __restrict__ agg0, const float* __restrict__ agg1,
    const float* __restrict__ normb, const float* __restrict__ Wm_s,
    const float* __restrict__ Wm_v, const float* __restrict__ Wu_s,
    const float* __restrict__ Wu_v, const float* __restrict__ Ws_s,
    const float* __restrict__ Ws_v, const float* __restrict__ res_scale_p,
    float* __restrict__ out, int N) {
  __shared__ float sWms[384];
  __shared__ float sWmv[64];
  __shared__ float sWus[256];
  __shared__ float sWuv[64];
  __shared__ float sWss[256];
  __shared__ float sWsv[64];
  int t = threadIdx.x;
  for (int i = t; i < 384; i += 256) sWms[i] = Wm_s[i];
  if (t < 64) sWmv[t] = Wm_v[t];
  sWus[t] = Wu_s[t];
  if (t < 64) sWuv[t] = Wu_v[t];
  sWss[t] = Ws_s[t];
  if (t < 64) sWsv[t] = Ws_v[t];
  __syncthreads();
  int n = blockIdx.x * 256 + t;
  if (n >= N) return;

  float inv = 1.0f / fmaxf(normb[n], EPSF);
  float4 a04[4], a14[6];
  {
    const float4* p = (const float4*)(agg0 + (long long)n * 16);
#pragma unroll
    for (int i = 0; i < 4; i++) a04[i] = p[i];
    const float4* q = (const float4*)(agg1 + (long long)n * 24);
#pragma unroll
    for (int i = 0; i < 6; i++) a14[i] = q[i];
  }
  float* a0 = (float*)a04;
  float* a1 = (float*)a14;
#pragma unroll
  for (int i = 0; i < 16; i++) a0[i] *= inv;
#pragma unroll
  for (int i = 0; i < 24; i++) a1[i] *= inv;

  float scal[16], gate[8];
#pragma unroll
  for (int jj = 0; jj < 24; jj++) {
    float acc = 0.f;
#pragma unroll
    for (int i = 0; i < 16; i++) acc += a0[i] * sWms[i * 24 + jj];
    acc *= Q16;
    if (jj < 16) scal[jj] = acc * sigm(acc);
    else gate[jj - 16] = sigm(acc);
  }
  float vg[24];
#pragma unroll
  for (int j = 0; j < 8; j++) {
    float g = gate[j];
#pragma unroll
    for (int cc = 0; cc < 3; cc++) {
      float acc = 0.f;
#pragma unroll
      for (int i = 0; i < 8; i++) acc += a1[i * 3 + cc] * sWmv[i * 8 + j];
      vg[j * 3 + cc] = acc * Q8 * g;
    }
  }
  float4 xn4[10], xo4[10];
  {
    const float4* p = (const float4*)(xnorm + (long long)n * 40);
    const float4* q = (const float4*)(x + (long long)n * 40);
#pragma unroll
    for (int i = 0; i < 10; i++) { xn4[i] = p[i]; xo4[i] = q[i]; }
  }
  const float* xn = (const float*)xn4;
  const float* xo = (const float*)xo4;
  float rs = res_scale_p[0];

  float4 ob[10];
  float* ov = (float*)ob;
#pragma unroll
  for (int j = 0; j < 16; j++) {
    float acc = 0.f, acc2 = 0.f;
#pragma unroll
    for (int i = 0; i < 16; i++) {
      acc += scal[i] * sWus[i * 16 + j];
      acc2 += xn[i] * sWss[i * 16 + j];
    }
    ov[j] = xo[j] + rs * ((acc + acc2) * Q16);
  }
#pragma unroll
  for (int j = 0; j < 8; j++) {
#pragma unroll
    for (int cc = 0; cc < 3; cc++) {
      float acc = 0.f;
#pragma unroll
      for (int i = 0; i < 8; i++)
        acc += vg[i * 3 + cc] * sWuv[i * 8 + j] + xn[16 + i * 3 + cc] * sWsv[i * 8 + j];
      ov[16 + j * 3 + cc] = xo[16 + j * 3 + cc] + rs * (acc * Q8);
    }
  }
  float4* po = (float4*)(out + (long long)n * 40);
#pragma unroll
  for (int i = 0; i < 10; i++) po[i] = ob[i];
}

// ---------------- launch ----------------
extern "C" void kernel_launch(void* const* d_in, const int* in_sizes, int n_in,
                              void* d_out, int out_size, void* d_ws, size_t ws_size,
                              hipStream_t stream) {
  const float* x = (const float*)d_in[0];
  const int* esrc = (const int*)d_in[1];
  const int* edst = (const int*)d_in[2];
  const float* sh = (const float*)d_in[3];
  const float* rbf = (const float*)d_in[4];
  const float* elen = (const float*)d_in[5];
  const float* w_r1 = (const float*)d_in[6];
  const float* b_r1 = (const float*)d_in[7];
  const float* w_r2 = (const float*)d_in[8];
  const float* b_r2 = (const float*)d_in[9];
  const float* w_g1 = (const float*)d_in[10];
  const float* b_g1 = (const float*)d_in[11];
  const float* w_g2 = (const float*)d_in[12];
  const float* b_g2 = (const float*)d_in[13];
  const float* Wm_s = (const float*)d_in[14];
  const float* Wm_v = (const float*)d_in[15];
  const float* Wu_s = (const float*)d_in[16];
  const float* Wu_v = (const float*)d_in[17];
  const float* Ws_s = (const float*)d_in[18];
  const float* Ws_v = (const float*)d_in[19];
  const float* res_scale = (const float*)d_in[20];

  const int N = in_sizes[0] / 40;
  const int E = in_sizes[1];

  char* ws = (char*)d_ws;
  size_t off = 0;
  float* xnorm = (float*)(ws + off); off += (size_t)N * 40 * sizeof(float);
  off = (off + 255) & ~(size_t)255;
  float* agg0 = (float*)(ws + off); off += (size_t)N * 16 * sizeof(float);
  float* agg1 = (float*)(ws + off); off += (size_t)N * 24 * sizeof(float);
  float* normb = (float*)(ws + off); off += (size_t)N * sizeof(float);
  off = (off + 255) & ~(size_t)255;
  f16* W2T = (f16*)(ws + off); off += (size_t)WNUM * 64 * sizeof(f16);

  // zero accumulators (agg0, agg1, normb are contiguous)
  hipMemsetAsync(agg0, 0, (size_t)N * 41 * sizeof(float), stream);

  k_prep_w2t<<<(HID * WNUM + 255) / 256, 256, 0, stream>>>(w_r2, W2T);
  k_xnorm<<<(N + 255) / 256, 256, 0, stream>>>(x, xnorm, N);

  int nblk = (E + 63) / 64;
  k_edge<<<nblk, 256, 0, stream>>>(xnorm, esrc, edst, sh, rbf, elen, w_r1, b_r1,
                                   w_g1, b_g1, w_g2, b_g2, b_r2, W2T, agg0, agg1,
                                   normb, E);

  k_node<<<(N + 255) / 256, 256, 0, stream>>>(x, xnorm, agg0, agg1, normb, Wm_s,
                                              Wm_v, Wu_s, Wu_v, Ws_s, Ws_v,
                                              res_scale, (float*)d_out, N);
}

// Round 2
// 524.508 us; speedup vs baseline: 1.1500x; 1.1500x over previous
//
#include <hip/hip_runtime.h>
#include <cstdint>

#define MUL0 16
#define MUL1 8
#define NRBF 8
#define HID 64
#define WNUM 576
#define CUTOFF 5.0f
#define EPSF 1e-8f

#define INV_SQRT3 0.57735026918962576f
#define A_PATH    0.20412414523193154f   /* 1/sqrt(24) */
#define Q16       0.25f                  /* 1/sqrt(16) */
#define Q8        0.35355339059327373f   /* 1/sqrt(8)  */
#define PI_OVER_CUT 0.62831853071795865f /* pi/5 */

typedef _Float16 f16;
typedef _Float16 f16x8 __attribute__((ext_vector_type(8)));
typedef float f32x4 __attribute__((ext_vector_type(4)));

__device__ __forceinline__ float sigm(float x) { return 1.0f / (1.0f + __expf(-x)); }

// ---------------- prep: w_r2 (64 x 576 f32) -> W2T (576 x 64 f16) ----------------
extern "C" __global__ __launch_bounds__(256) void k_prep_w2t(
    const float* __restrict__ w_r2, f16* __restrict__ W2T) {
  int t = blockIdx.x * 256 + threadIdx.x;
  if (t >= HID * WNUM) return;
  int n = t >> 6, k = t & 63;
  W2T[n * 64 + k] = (f16)w_r2[k * WNUM + n];
}

// ---------------- node irrep norm (vectorized) ----------------
extern "C" __global__ __launch_bounds__(256) void k_xnorm(
    const float* __restrict__ x, float* __restrict__ xnorm, int N) {
  int n = blockIdx.x * 256 + threadIdx.x;
  if (n >= N) return;
  const float4* xr = (const float4*)(x + (long long)n * 40);
  float4 vv[10];
#pragma unroll
  for (int i = 0; i < 10; i++) vv[i] = xr[i];
  float* f = (float*)vv;
  float ss = 0.f, vs = 0.f;
#pragma unroll
  for (int i = 0; i < 16; i++) ss += f[i] * f[i];
#pragma unroll
  for (int i = 16; i < 40; i++) vs += f[i] * f[i];
  float sr = rsqrtf(ss * (1.0f / 16.0f) + EPSF);
  float vr = rsqrtf(vs * (1.0f / 8.0f) + EPSF);
#pragma unroll
  for (int i = 0; i < 16; i++) f[i] *= sr;
#pragma unroll
  for (int i = 16; i < 40; i++) f[i] *= vr;
  float4* o = (float4*)(xnorm + (long long)n * 40);
#pragma unroll
  for (int i = 0; i < 10; i++) o[i] = vv[i];
}

// ---------------- fused edge kernel: barriered, wave-local work split ----------------
// block = 256 threads = 4 waves; each wave owns 16 edges end-to-end, but
// block-wide __syncthreads keeps the 4 waves' W2T sweep + atomic bursts
// time-aligned (cache locality — removing them blew FETCH up 13x in R1).
extern "C" __global__ __launch_bounds__(256) void k_edge(
    const float* __restrict__ xnorm, const int* __restrict__ esrc,
    const int* __restrict__ edst, const float* __restrict__ sh,
    const float* __restrict__ rbf, const float* __restrict__ elen,
    const float* __restrict__ w_r1, const float* __restrict__ b_r1,
    const float* __restrict__ w_g1, const float* __restrict__ b_g1,
    const float* __restrict__ w_g2, const float* __restrict__ b_g2,
    const float* __restrict__ b_r2, const f16* __restrict__ W2T,
    float* __restrict__ agg0, float* __restrict__ agg1,
    float* __restrict__ normb, int E) {
  // strides padded so quad-spaced rows land on distinct banks (R1-verified:
  // SQ_LDS_BANK_CONFLICT 1.1e7 -> 4e5)
  __shared__ __align__(16) f16   s_H[4][16][72];    // H, row = edge
  __shared__ __align__(16) float s_sn[4][16][20];   // raw normalized scalars
  __shared__ __align__(16) float s_v[4][16][28];    // raw normalized vectors (24 used)
  __shared__ __align__(16) float s_a1[4][16][12];   // INV_SQRT3 * (v . sh1), 8 used
  __shared__ __align__(16) float s_sh[4][16][4];
  __shared__ __align__(16) float s_rbf[4][16][8];
  __shared__ float s_ew[4][16];
  __shared__ int   s_dst[4][16];

  const int t = threadIdx.x;
  const int w = t >> 6;
  const int lane = t & 63;
  const long long eb = (long long)blockIdx.x * 64 + w * 16;  // wave's first edge

  // ---- A0: staging (wave-local slices, block-wide barrier after) ----
  const int ge_l = lane >> 2;       // local edge for gather (0..15)
  const int part = lane & 3;        // which chunk of the 40-float row
  const long long ge = eb + ge_l;
  int srcn = 0;
  float4 shv = {0.f, 0.f, 0.f, 0.f};
  if (ge < E) {
    srcn = esrc[ge];
    shv = *(const float4*)&sh[ge * 4];
  }
  {
    long long gb = eb * 8 + lane;
    float r0 = (gb < (long long)E * 8) ? rbf[gb] : 0.f;
    float r1 = (gb + 64 < (long long)E * 8) ? rbf[gb + 64] : 0.f;
    (&s_rbf[w][0][0])[lane] = r0;
    (&s_rbf[w][0][0])[lane + 64] = r1;
    long long gs = eb * 4 + lane;
    (&s_sh[w][0][0])[lane] = (gs < (long long)E * 4) ? sh[gs] : 0.f;
    if (lane < 16) {
      long long g2 = eb + lane;
      s_dst[w][lane] = (g2 < E) ? edst[g2] : 0;
    }
  }
  __syncthreads();

  // ---- A1: gather + transform (4 lanes per edge, float4 loads) ----
  {
    const float* xr = xnorm + (long long)srcn * 40;
    if (part < 2) {
      float4 aLo = *(const float4*)(xr + part * 8);
      float4 aHi = *(const float4*)(xr + part * 8 + 4);
      *(float4*)&s_sn[w][ge_l][part * 8] = aLo;
      *(float4*)&s_sn[w][ge_l][part * 8 + 4] = aHi;
    } else {
      const int i0 = (part - 2) * 4;  // 0 or 4
      const float* vp = xr + 16 + i0 * 3;
      float4 v0 = *(const float4*)(vp);
      float4 v1 = *(const float4*)(vp + 4);
      float4 v2 = *(const float4*)(vp + 8);
      *(float4*)&s_v[w][ge_l][i0 * 3] = v0;
      *(float4*)&s_v[w][ge_l][i0 * 3 + 4] = v1;
      *(float4*)&s_v[w][ge_l][i0 * 3 + 8] = v2;
      float s1x = shv.y, s1y = shv.z, s1z = shv.w;
      s_a1[w][ge_l][i0]     = INV_SQRT3 * (v0.x * s1x + v0.y * s1y + v0.z * s1z);
      s_a1[w][ge_l][i0 + 1] = INV_SQRT3 * (v0.w * s1x + v1.x * s1y + v1.y * s1z);
      s_a1[w][ge_l][i0 + 2] = INV_SQRT3 * (v1.z * s1x + v1.w * s1y + v2.x * s1z);
      s_a1[w][ge_l][i0 + 3] = INV_SQRT3 * (v2.y * s1x + v2.z * s1y + v2.w * s1z);
    }
  }

  // ---- A2: hidden layer H (f16), lane = h, 16 edges of this wave ----
  {
    float wr[8];
#pragma unroll
    for (int r = 0; r < 8; r++) wr[r] = w_r1[r * HID + lane];
    float bh = b_r1[lane];
#pragma unroll
    for (int u = 0; u < 16; u++) {
      float4 ra = *(const float4*)&s_rbf[w][u][0];
      float4 rb = *(const float4*)&s_rbf[w][u][4];
      float acc = bh + ra.x * wr[0] + ra.y * wr[1] + ra.z * wr[2] + ra.w * wr[3]
                     + rb.x * wr[4] + rb.y * wr[5] + rb.z * wr[6] + rb.w * wr[7];
      s_H[w][u][lane] = (f16)(acc * sigm(acc));
    }
  }

  // ---- A3: gate MLP, all 64 lanes (16 h-units per lane) + shfl reduce ----
  {
    const int eg = lane & 15;
    const int grp = lane >> 4;
    float4 ga = *(const float4*)&s_rbf[w][eg][0];
    float4 gb = *(const float4*)&s_rbf[w][eg][4];
    float rv[8] = {ga.x, ga.y, ga.z, ga.w, gb.x, gb.y, gb.z, gb.w};
    float tt[16];
    {
      const float4 b0 = *(const float4*)&b_g1[grp * 16];
      const float4 b1 = *(const float4*)&b_g1[grp * 16 + 4];
      const float4 b2 = *(const float4*)&b_g1[grp * 16 + 8];
      const float4 b3 = *(const float4*)&b_g1[grp * 16 + 12];
      tt[0] = b0.x; tt[1] = b0.y; tt[2] = b0.z; tt[3] = b0.w;
      tt[4] = b1.x; tt[5] = b1.y; tt[6] = b1.z; tt[7] = b1.w;
      tt[8] = b2.x; tt[9] = b2.y; tt[10] = b2.z; tt[11] = b2.w;
      tt[12] = b3.x; tt[13] = b3.y; tt[14] = b3.z; tt[15] = b3.w;
    }
#pragma unroll
    for (int r = 0; r < 8; r++) {
      const float* wg = w_g1 + r * HID + grp * 16;
      float4 w0 = *(const float4*)(wg);
      float4 w1 = *(const float4*)(wg + 4);
      float4 w2 = *(const float4*)(wg + 8);
      float4 w3 = *(const float4*)(wg + 12);
      float rr = rv[r];
      tt[0] += rr * w0.x; tt[1] += rr * w0.y; tt[2] += rr * w0.z; tt[3] += rr * w0.w;
      tt[4] += rr * w1.x; tt[5] += rr * w1.y; tt[6] += rr * w1.z; tt[7] += rr * w1.w;
      tt[8] += rr * w2.x; tt[9] += rr * w2.y; tt[10] += rr * w2.z; tt[11] += rr * w2.w;
      tt[12] += rr * w3.x; tt[13] += rr * w3.y; tt[14] += rr * w3.z; tt[15] += rr * w3.w;
    }
    float gw[16];
    {
      const float4 g0 = *(const float4*)&w_g2[grp * 16];
      const float4 g1 = *(const float4*)&w_g2[grp * 16 + 4];
      const float4 g2 = *(const float4*)&w_g2[grp * 16 + 8];
      const float4 g3 = *(const float4*)&w_g2[grp * 16 + 12];
      gw[0] = g0.x; gw[1] = g0.y; gw[2] = g0.z; gw[3] = g0.w;
      gw[4] = g1.x; gw[5] = g1.y; gw[6] = g1.z; gw[7] = g1.w;
      gw[8] = g2.x; gw[9] = g2.y; gw[10] = g2.z; gw[11] = g2.w;
      gw[12] = g3.x; gw[13] = g3.y; gw[14] = g3.z; gw[15] = g3.w;
    }
    float accp = 0.f;
#pragma unroll
    for (int k = 0; k < 16; k++) accp += tt[k] * sigm(tt[k]) * gw[k];
    accp += __shfl_xor(accp, 16);
    accp += __shfl_xor(accp, 32);
    if (lane < 16) {
      long long g2e = eb + lane;
      float ew = 0.f;
      if (g2e < E) {
        float len = elen[g2e];
        float cw = (len < CUTOFF) ? 0.5f * (__cosf(PI_OVER_CUT * len) + 1.0f) : 0.f;
        ew = cw * sigm(accp + b_g2[0]);
      }
      s_ew[w][lane] = ew;
    }
  }
  __syncthreads();

  // ---- B: MFMA over 36 j-tiles, fully unrolled so loads pipeline ----
  const int quad = lane >> 4;
  const int c = lane & 15;

  const f16x8 af0 = *(const f16x8*)&s_H[w][c][quad * 8];
  const f16x8 af1 = *(const f16x8*)&s_H[w][c][32 + quad * 8];

  float p1[4] = {0.f, 0.f, 0.f, 0.f};   // w1 path (x sh0 at epilogue)
  float p2[4] = {0.f, 0.f, 0.f, 0.f};   // w2 path
  float t3[4] = {0.f, 0.f, 0.f, 0.f};   // w3 path (x sh1 at epilogue)
  float mx[4] = {0.f, 0.f, 0.f, 0.f};   // w4 path (x sh0 at epilogue)
  float my[4] = {0.f, 0.f, 0.f, 0.f};
  float mz[4] = {0.f, 0.f, 0.f, 0.f};

  const f16* wb = W2T + (long long)c * 64 + quad * 8;
  const float* bp = b_r2 + c;

#pragma unroll
  for (int jt = 0; jt < 36; jt++) {
    const f16* nb = wb + jt * 1024;
    f16x8 b0 = *(const f16x8*)(nb);
    f16x8 b1 = *(const f16x8*)(nb + 32);
    float bias = bp[jt * 16];
    f32x4 C = {0.f, 0.f, 0.f, 0.f};
    C = __builtin_amdgcn_mfma_f32_16x16x32_f16(af0, b0, C, 0, 0, 0);
    C = __builtin_amdgcn_mfma_f32_16x16x32_f16(af1, b1, C, 0, 0, 0);
    if (jt < 16) {
#pragma unroll
      for (int r = 0; r < 4; r++)
        p1[r] += s_sn[w][quad * 4 + r][jt] * (C[r] + bias);
    } else if (jt < 24) {
      const int i = jt - 16;
#pragma unroll
      for (int r = 0; r < 4; r++)
        p2[r] += s_a1[w][quad * 4 + r][i] * (C[r] + bias);
    } else if (jt < 32) {
      const int i = (jt - 24) * 2 + (c >> 3);
#pragma unroll
      for (int r = 0; r < 4; r++)
        t3[r] += s_sn[w][quad * 4 + r][i] * (C[r] + bias);
    } else {
      const int i = (jt - 32) * 2 + (c >> 3);
#pragma unroll
      for (int r = 0; r < 4; r++) {
        float wvv = C[r] + bias;
        mx[r] += s_v[w][quad * 4 + r][3 * i] * wvv;
        my[r] += s_v[w][quad * 4 + r][3 * i + 1] * wvv;
        mz[r] += s_v[w][quad * 4 + r][3 * i + 2] * wvv;
      }
    }
  }

  // fold the two column-halves (c and c^8 share output j = c&7)
#pragma unroll
  for (int r = 0; r < 4; r++) {
    t3[r] += __shfl_xor(t3[r], 8);
    mx[r] += __shfl_xor(mx[r], 8);
    my[r] += __shfl_xor(my[r], 8);
    mz[r] += __shfl_xor(mz[r], 8);
  }

  // ---- epilogue: scale + atomic scatter ----
#pragma unroll
  for (int r = 0; r < 4; r++) {
    const int e = quad * 4 + r;
    float ew = s_ew[w][e];
    float sc = A_PATH * ew;
    int dst = s_dst[w][e];
    float sh0 = s_sh[w][e][0];
    atomicAdd(&agg0[(long long)dst * 16 + c], (sh0 * p1[r] + p2[r]) * sc);
    if (c < 8) {
      float t3v = t3[r] * sc;
      float scs = sc * sh0;
      float ox = t3v * s_sh[w][e][1] + mx[r] * scs;
      float oy = t3v * s_sh[w][e][2] + my[r] * scs;
      float oz = t3v * s_sh[w][e][3] + mz[r] * scs;
      long long b = (long long)dst * 24 + (long long)c * 3;
      atomicAdd(&agg1[b], ox);
      atomicAdd(&agg1[b + 1], oy);
      atomicAdd(&agg1[b + 2], oz);
    } else if (c == 8) {
      atomicAdd(&normb[dst], ew);
    }
  }
}

// ---------------- final node kernel (vectorized loads/stores) ----------------
extern "C" __global__ __launch_bounds__(256) void k_node(
    const float* __restrict__ x, const float* __restrict__ xnorm,
    const float* __restrict__ agg0, const float* __restrict__ agg1,
    const float* __restrict__ normb, const float* __restrict__ Wm_s,
    const float* __restrict__ Wm_v, const float* __restrict__ Wu_s,
    const float* __restrict__ Wu_v, const float* __restrict__ Ws_s,
    const float* __restrict__ Ws_v, const float* __restrict__ res_scale_p,
    float* __restrict__ out, int N) {
  __shared__ float sWms[384];
  __shared__ float sWmv[64];
  __shared__ float sWus[256];
  __shared__ float sWuv[64];
  __shared__ float sWss[256];
  __shared__ float sWsv[64];
  int t = threadIdx.x;
  for (int i = t; i < 384; i += 256) sWms[i] = Wm_s[i];
  if (t < 64) sWmv[t] = Wm_v[t];
  sWus[t] = Wu_s[t];
  if (t < 64) sWuv[t] = Wu_v[t];
  sWss[t] = Ws_s[t];
  if (t < 64) sWsv[t] = Ws_v[t];
  __syncthreads();
  int n = blockIdx.x * 256 + t;
  if (n >= N) return;

  float inv = 1.0f / fmaxf(normb[n], EPSF);
  float4 a04[4], a14[6];
  {
    const float4* p = (const float4*)(agg0 + (long long)n * 16);
#pragma unroll
    for (int i = 0; i < 4; i++) a04[i] = p[i];
    const float4* q = (const float4*)(agg1 + (long long)n * 24);
#pragma unroll
    for (int i = 0; i < 6; i++) a14[i] = q[i];
  }
  float* a0 = (float*)a04;
  float* a1 = (float*)a14;
#pragma unroll
  for (int i = 0; i < 16; i++) a0[i] *= inv;
#pragma unroll
  for (int i = 0; i < 24; i++) a1[i] *= inv;

  float scal[16], gate[8];
#pragma unroll
  for (int jj = 0; jj < 24; jj++) {
    float acc = 0.f;
#pragma unroll
    for (int i = 0; i < 16; i++) acc += a0[i] * sWms[i * 24 + jj];
    acc *= Q16;
    if (jj < 16) scal[jj] = acc * sigm(acc);
    else gate[jj - 16] = sigm(acc);
  }
  float vg[24];
#pragma unroll
  for (int j = 0; j < 8; j++) {
    float g = gate[j];
#pragma unroll
    for (int cc = 0; cc < 3; cc++) {
      float acc = 0.f;
#pragma unroll
      for (int i = 0; i < 8; i++) acc += a1[i * 3 + cc] * sWmv[i * 8 + j];
      vg[j * 3 + cc] = acc * Q8 * g;
    }
  }
  float4 xn4[10], xo4[10];
  {
    const float4* p = (const float4*)(xnorm + (long long)n * 40);
    const float4* q = (const float4*)(x + (long long)n * 40);
#pragma unroll
    for (int i = 0; i < 10; i++) { xn4[i] = p[i]; xo4[i] = q[i]; }
  }
  const float* xn = (const float*)xn4;
  const float* xo = (const float*)xo4;
  float rs = res_scale_p[0];

  float4 ob[10];
  float* ov = (float*)ob;
#pragma unroll
  for (int j = 0; j < 16; j++) {
    float acc = 0.f, acc2 = 0.f;
#pragma unroll
    for (int i = 0; i < 16; i++) {
      acc += scal[i] * sWus[i * 16 + j];
      acc2 += xn[i] * sWss[i * 16 + j];
    }
    ov[j] = xo[j] + rs * ((acc + acc2) * Q16);
  }
#pragma unroll
  for (int j = 0; j < 8; j++) {
#pragma unroll
    for (int cc = 0; cc < 3; cc++) {
      float acc = 0.f;
#pragma unroll
      for (int i = 0; i < 8; i++)
        acc += vg[i * 3 + cc] * sWuv[i * 8 + j] + xn[16 + i * 3 + cc] * sWsv[i * 8 + j];
      ov[16 + j * 3 + cc] = xo[16 + j * 3 + cc] + rs * (acc * Q8);
    }
  }
  float4* po = (float4*)(out + (long long)n * 40);
#pragma unroll
  for (int i = 0; i < 10; i++) po[i] = ob[i];
}

// ---------------- launch ----------------
extern "C" void kernel_launch(void* const* d_in, const int* in_sizes, int n_in,
                              void* d_out, int out_size, void* d_ws, size_t ws_size,
                              hipStream_t stream) {
  const float* x = (const float*)d_in[0];
  const int* esrc = (const int*)d_in[1];
  const int* edst = (const int*)d_in[2];
  const float* sh = (const float*)d_in[3];
  const float* rbf = (const float*)d_in[4];
  const float* elen = (const float*)d_in[5];
  const float* w_r1 = (const float*)d_in[6];
  const float* b_r1 = (const float*)d_in[7];
  const float* w_r2 = (const float*)d_in[8];
  const float* b_r2 = (const float*)d_in[9];
  const float* w_g1 = (const float*)d_in[10];
  const float* b_g1 = (const float*)d_in[11];
  const float* w_g2 = (const float*)d_in[12];
  const float* b_g2 = (const float*)d_in[13];
  const float* Wm_s = (const float*)d_in[14];
  const float* Wm_v = (const float*)d_in[15];
  const float* Wu_s = (const float*)d_in[16];
  const float* Wu_v = (const float*)d_in[17];
  const float* Ws_s = (const float*)d_in[18];
  const float* Ws_v = (const float*)d_in[19];
  const float* res_scale = (const float*)d_in[20];

  const int N = in_sizes[0] / 40;
  const int E = in_sizes[1];

  char* ws = (char*)d_ws;
  size_t off = 0;
  float* xnorm = (float*)(ws + off); off += (size_t)N * 40 * sizeof(float);
  off = (off + 255) & ~(size_t)255;
  float* agg0 = (float*)(ws + off); off += (size_t)N * 16 * sizeof(float);
  float* agg1 = (float*)(ws + off); off += (size_t)N * 24 * sizeof(float);
  float* normb = (float*)(ws + off); off += (size_t)N * sizeof(float);
  off = (off + 255) & ~(size_t)255;
  f16* W2T = (f16*)(ws + off); off += (size_t)WNUM * 64 * sizeof(f16);

  // zero accumulators (agg0, agg1, normb are contiguous)
  hipMemsetAsync(agg0, 0, (size_t)N * 41 * sizeof(float), stream);

  k_prep_w2t<<<(HID * WNUM + 255) / 256, 256, 0, stream>>>(w_r2, W2T);
  k_xnorm<<<(N + 255) / 256, 256, 0, stream>>>(x, xnorm, N);

  int nblk = (E + 63) / 64;
  k_edge<<<nblk, 256, 0, stream>>>(xnorm, esrc, edst, sh, rbf, elen, w_r1, b_r1,
                                   w_g1, b_g1, w_g2, b_g2, b_r2, W2T, agg0, agg1,
                                   normb, E);

  k_node<<<(N + 255) / 256, 256, 0, stream>>>(x, xnorm, agg0, agg1, normb, Wm_s,
                                              Wm_v, Wu_s, Wu_v, Ws_s, Ws_v,
                                              res_scale, (float*)d_out, N);
}

// Round 3
// 404.221 us; speedup vs baseline: 1.4922x; 1.2976x over previous
//
#include <hip/hip_runtime.h>
#include <cstdint>

#define MUL0 16
#define MUL1 8
#define NRBF 8
#define HID 64
#define WNUM 576
#define CUTOFF 5.0f
#define EPSF 1e-8f

#define INV_SQRT3 0.57735026918962576f
#define A_PATH    0.20412414523193154f   /* 1/sqrt(24) */
#define Q16       0.25f                  /* 1/sqrt(16) */
#define Q8        0.35355339059327373f   /* 1/sqrt(8)  */
#define PI_OVER_CUT 0.62831853071795865f /* pi/5 */

typedef _Float16 f16;
typedef _Float16 f16x8 __attribute__((ext_vector_type(8)));
typedef float f32x4 __attribute__((ext_vector_type(4)));

__device__ __forceinline__ float sigm(float x) { return 1.0f / (1.0f + __expf(-x)); }

// ---------------- prep: w_r2 (64 x 576 f32) -> W2T (576 x 64 f16) ----------------
extern "C" __global__ __launch_bounds__(256) void k_prep_w2t(
    const float* __restrict__ w_r2, f16* __restrict__ W2T) {
  int t = blockIdx.x * 256 + threadIdx.x;
  if (t >= HID * WNUM) return;
  int n = t >> 6, k = t & 63;
  W2T[n * 64 + k] = (f16)w_r2[k * WNUM + n];
}

// ---------------- node irrep norm (vectorized) ----------------
extern "C" __global__ __launch_bounds__(256) void k_xnorm(
    const float* __restrict__ x, float* __restrict__ xnorm, int N) {
  int n = blockIdx.x * 256 + threadIdx.x;
  if (n >= N) return;
  const float4* xr = (const float4*)(x + (long long)n * 40);
  float4 vv[10];
#pragma unroll
  for (int i = 0; i < 10; i++) vv[i] = xr[i];
  float* f = (float*)vv;
  float ss = 0.f, vs = 0.f;
#pragma unroll
  for (int i = 0; i < 16; i++) ss += f[i] * f[i];
#pragma unroll
  for (int i = 16; i < 40; i++) vs += f[i] * f[i];
  float sr = rsqrtf(ss * (1.0f / 16.0f) + EPSF);
  float vr = rsqrtf(vs * (1.0f / 8.0f) + EPSF);
#pragma unroll
  for (int i = 0; i < 16; i++) f[i] *= sr;
#pragma unroll
  for (int i = 16; i < 40; i++) f[i] *= vr;
  float4* o = (float4*)(xnorm + (long long)n * 40);
#pragma unroll
  for (int i = 0; i < 10; i++) o[i] = vv[i];
}

// ---------------- fused edge kernel ----------------
// block = 256 threads = 4 waves; each wave owns 16 edges. Block-wide barriers
// keep the 4 waves' W2T sweep + atomic bursts time-aligned (R1: removing them
// blew FETCH up 13x). launch_bounds(256,5) pins VGPR <= ~102 so 5 blocks/CU
// stay resident (R2: full unroll -> 168 VGPR -> 11.6% occupancy -> 423 us).
extern "C" __global__ __launch_bounds__(256, 5) void k_edge(
    const float* __restrict__ xnorm, const int* __restrict__ esrc,
    const int* __restrict__ edst, const float* __restrict__ sh,
    const float* __restrict__ rbf, const float* __restrict__ elen,
    const float* __restrict__ w_r1, const float* __restrict__ b_r1,
    const float* __restrict__ w_g1, const float* __restrict__ b_g1,
    const float* __restrict__ w_g2, const float* __restrict__ b_g2,
    const float* __restrict__ b_r2, const f16* __restrict__ W2T,
    float* __restrict__ agg0, float* __restrict__ agg1,
    float* __restrict__ normb, int E) {
  // strides padded so quad-spaced rows land on distinct banks (R1-verified:
  // SQ_LDS_BANK_CONFLICT 1.1e7 -> 4e5)
  __shared__ __align__(16) f16   s_H[4][16][72];    // H, row = edge
  __shared__ __align__(16) float s_sn[4][16][20];   // raw normalized scalars
  __shared__ __align__(16) float s_v[4][16][28];    // raw normalized vectors (24 used)
  __shared__ __align__(16) float s_a1[4][16][12];   // INV_SQRT3 * (v . sh1), 8 used
  __shared__ __align__(16) float s_sh[4][16][4];
  __shared__ __align__(16) float s_rbf[4][16][8];
  __shared__ float s_ew[4][16];
  __shared__ int   s_dst[4][16];

  const int t = threadIdx.x;
  const int w = t >> 6;
  const int lane = t & 63;
  const long long eb = (long long)blockIdx.x * 64 + w * 16;  // wave's first edge

  // ---- A0: staging (wave-local slices, block-wide barrier after) ----
  const int ge_l = lane >> 2;       // local edge for gather (0..15)
  const int part = lane & 3;        // which chunk of the 40-float row
  const long long ge = eb + ge_l;
  int srcn = 0;
  float4 shv = {0.f, 0.f, 0.f, 0.f};
  if (ge < E) {
    srcn = esrc[ge];
    shv = *(const float4*)&sh[ge * 4];
  }
  {
    long long gb = eb * 8 + lane;
    float r0 = (gb < (long long)E * 8) ? rbf[gb] : 0.f;
    float r1 = (gb + 64 < (long long)E * 8) ? rbf[gb + 64] : 0.f;
    (&s_rbf[w][0][0])[lane] = r0;
    (&s_rbf[w][0][0])[lane + 64] = r1;
    long long gs = eb * 4 + lane;
    (&s_sh[w][0][0])[lane] = (gs < (long long)E * 4) ? sh[gs] : 0.f;
    if (lane < 16) {
      long long g2 = eb + lane;
      s_dst[w][lane] = (g2 < E) ? edst[g2] : 0;
    }
  }
  __syncthreads();

  // ---- A1: gather + transform (4 lanes per edge, float4 loads) ----
  {
    const float* xr = xnorm + (long long)srcn * 40;
    if (part < 2) {
      float4 aLo = *(const float4*)(xr + part * 8);
      float4 aHi = *(const float4*)(xr + part * 8 + 4);
      *(float4*)&s_sn[w][ge_l][part * 8] = aLo;
      *(float4*)&s_sn[w][ge_l][part * 8 + 4] = aHi;
    } else {
      const int i0 = (part - 2) * 4;  // 0 or 4
      const float* vp = xr + 16 + i0 * 3;
      float4 v0 = *(const float4*)(vp);
      float4 v1 = *(const float4*)(vp + 4);
      float4 v2 = *(const float4*)(vp + 8);
      *(float4*)&s_v[w][ge_l][i0 * 3] = v0;
      *(float4*)&s_v[w][ge_l][i0 * 3 + 4] = v1;
      *(float4*)&s_v[w][ge_l][i0 * 3 + 8] = v2;
      float s1x = shv.y, s1y = shv.z, s1z = shv.w;
      s_a1[w][ge_l][i0]     = INV_SQRT3 * (v0.x * s1x + v0.y * s1y + v0.z * s1z);
      s_a1[w][ge_l][i0 + 1] = INV_SQRT3 * (v0.w * s1x + v1.x * s1y + v1.y * s1z);
      s_a1[w][ge_l][i0 + 2] = INV_SQRT3 * (v1.z * s1x + v1.w * s1y + v2.x * s1z);
      s_a1[w][ge_l][i0 + 3] = INV_SQRT3 * (v2.y * s1x + v2.z * s1y + v2.w * s1z);
    }
  }

  // ---- A2: hidden layer H (f16), lane = h, 16 edges of this wave ----
  {
    float wr[8];
#pragma unroll
    for (int r = 0; r < 8; r++) wr[r] = w_r1[r * HID + lane];
    float bh = b_r1[lane];
#pragma unroll
    for (int u = 0; u < 16; u++) {
      float4 ra = *(const float4*)&s_rbf[w][u][0];
      float4 rb = *(const float4*)&s_rbf[w][u][4];
      float acc = bh + ra.x * wr[0] + ra.y * wr[1] + ra.z * wr[2] + ra.w * wr[3]
                     + rb.x * wr[4] + rb.y * wr[5] + rb.z * wr[6] + rb.w * wr[7];
      s_H[w][u][lane] = (f16)(acc * sigm(acc));
    }
  }

  // ---- A3: gate MLP, all 64 lanes (16 h-units per lane) + shfl reduce ----
  {
    const int eg = lane & 15;
    const int grp = lane >> 4;
    float4 ga = *(const float4*)&s_rbf[w][eg][0];
    float4 gb = *(const float4*)&s_rbf[w][eg][4];
    float rv[8] = {ga.x, ga.y, ga.z, ga.w, gb.x, gb.y, gb.z, gb.w};
    float tt[16];
    {
      const float4 b0 = *(const float4*)&b_g1[grp * 16];
      const float4 b1 = *(const float4*)&b_g1[grp * 16 + 4];
      const float4 b2 = *(const float4*)&b_g1[grp * 16 + 8];
      const float4 b3 = *(const float4*)&b_g1[grp * 16 + 12];
      tt[0] = b0.x; tt[1] = b0.y; tt[2] = b0.z; tt[3] = b0.w;
      tt[4] = b1.x; tt[5] = b1.y; tt[6] = b1.z; tt[7] = b1.w;
      tt[8] = b2.x; tt[9] = b2.y; tt[10] = b2.z; tt[11] = b2.w;
      tt[12] = b3.x; tt[13] = b3.y; tt[14] = b3.z; tt[15] = b3.w;
    }
#pragma unroll
    for (int r = 0; r < 8; r++) {
      const float* wg = w_g1 + r * HID + grp * 16;
      float4 w0 = *(const float4*)(wg);
      float4 w1 = *(const float4*)(wg + 4);
      float4 w2 = *(const float4*)(wg + 8);
      float4 w3 = *(const float4*)(wg + 12);
      float rr = rv[r];
      tt[0] += rr * w0.x; tt[1] += rr * w0.y; tt[2] += rr * w0.z; tt[3] += rr * w0.w;
      tt[4] += rr * w1.x; tt[5] += rr * w1.y; tt[6] += rr * w1.z; tt[7] += rr * w1.w;
      tt[8] += rr * w2.x; tt[9] += rr * w2.y; tt[10] += rr * w2.z; tt[11] += rr * w2.w;
      tt[12] += rr * w3.x; tt[13] += rr * w3.y; tt[14] += rr * w3.z; tt[15] += rr * w3.w;
    }
    float gw[16];
    {
      const float4 g0 = *(const float4*)&w_g2[grp * 16];
      const float4 g1 = *(const float4*)&w_g2[grp * 16 + 4];
      const float4 g2 = *(const float4*)&w_g2[grp * 16 + 8];
      const float4 g3 = *(const float4*)&w_g2[grp * 16 + 12];
      gw[0] = g0.x; gw[1] = g0.y; gw[2] = g0.z; gw[3] = g0.w;
      gw[4] = g1.x; gw[5] = g1.y; gw[6] = g1.z; gw[7] = g1.w;
      gw[8] = g2.x; gw[9] = g2.y; gw[10] = g2.z; gw[11] = g2.w;
      gw[12] = g3.x; gw[13] = g3.y; gw[14] = g3.z; gw[15] = g3.w;
    }
    float accp = 0.f;
#pragma unroll
    for (int k = 0; k < 16; k++) accp += tt[k] * sigm(tt[k]) * gw[k];
    accp += __shfl_xor(accp, 16);
    accp += __shfl_xor(accp, 32);
    if (lane < 16) {
      long long g2e = eb + lane;
      float ew = 0.f;
      if (g2e < E) {
        float len = elen[g2e];
        float cw = (len < CUTOFF) ? 0.5f * (__cosf(PI_OVER_CUT * len) + 1.0f) : 0.f;
        ew = cw * sigm(accp + b_g2[0]);
      }
      s_ew[w][lane] = ew;
    }
  }
  __syncthreads();

  // ---- B: MFMA over 36 j-tiles, four branch-free class loops ----
  const int quad = lane >> 4;
  const int c = lane & 15;

  const f16x8 af0 = *(const f16x8*)&s_H[w][c][quad * 8];
  const f16x8 af1 = *(const f16x8*)&s_H[w][c][32 + quad * 8];

  float p1[4] = {0.f, 0.f, 0.f, 0.f};   // w1 path (x sh0 at epilogue)
  float p2[4] = {0.f, 0.f, 0.f, 0.f};   // w2 path
  float t3[4] = {0.f, 0.f, 0.f, 0.f};   // w3 path (x sh1 at epilogue)
  float mx[4] = {0.f, 0.f, 0.f, 0.f};   // w4 path (x sh0 at epilogue)
  float my[4] = {0.f, 0.f, 0.f, 0.f};
  float mz[4] = {0.f, 0.f, 0.f, 0.f};

  const f16* wb = W2T + (long long)c * 64 + quad * 8;
  const float* bp = b_r2 + c;

#pragma unroll 2
  for (int jt = 0; jt < 16; jt++) {
    f16x8 b0 = *(const f16x8*)(wb + jt * 1024);
    f16x8 b1 = *(const f16x8*)(wb + jt * 1024 + 32);
    float bias = bp[jt * 16];
    f32x4 C = {0.f, 0.f, 0.f, 0.f};
    C = __builtin_amdgcn_mfma_f32_16x16x32_f16(af0, b0, C, 0, 0, 0);
    C = __builtin_amdgcn_mfma_f32_16x16x32_f16(af1, b1, C, 0, 0, 0);
#pragma unroll
    for (int r = 0; r < 4; r++)
      p1[r] += s_sn[w][quad * 4 + r][jt] * (C[r] + bias);
  }
#pragma unroll 2
  for (int jt = 16; jt < 24; jt++) {
    f16x8 b0 = *(const f16x8*)(wb + jt * 1024);
    f16x8 b1 = *(const f16x8*)(wb + jt * 1024 + 32);
    float bias = bp[jt * 16];
    f32x4 C = {0.f, 0.f, 0.f, 0.f};
    C = __builtin_amdgcn_mfma_f32_16x16x32_f16(af0, b0, C, 0, 0, 0);
    C = __builtin_amdgcn_mfma_f32_16x16x32_f16(af1, b1, C, 0, 0, 0);
    const int i = jt - 16;
#pragma unroll
    for (int r = 0; r < 4; r++)
      p2[r] += s_a1[w][quad * 4 + r][i] * (C[r] + bias);
  }
#pragma unroll 2
  for (int jt = 24; jt < 32; jt++) {
    f16x8 b0 = *(const f16x8*)(wb + jt * 1024);
    f16x8 b1 = *(const f16x8*)(wb + jt * 1024 + 32);
    float bias = bp[jt * 16];
    f32x4 C = {0.f, 0.f, 0.f, 0.f};
    C = __builtin_amdgcn_mfma_f32_16x16x32_f16(af0, b0, C, 0, 0, 0);
    C = __builtin_amdgcn_mfma_f32_16x16x32_f16(af1, b1, C, 0, 0, 0);
    const int i = (jt - 24) * 2 + (c >> 3);
#pragma unroll
    for (int r = 0; r < 4; r++)
      t3[r] += s_sn[w][quad * 4 + r][i] * (C[r] + bias);
  }
#pragma unroll 2
  for (int jt = 32; jt < 36; jt++) {
    f16x8 b0 = *(const f16x8*)(wb + jt * 1024);
    f16x8 b1 = *(const f16x8*)(wb + jt * 1024 + 32);
    float bias = bp[jt * 16];
    f32x4 C = {0.f, 0.f, 0.f, 0.f};
    C = __builtin_amdgcn_mfma_f32_16x16x32_f16(af0, b0, C, 0, 0, 0);
    C = __builtin_amdgcn_mfma_f32_16x16x32_f16(af1, b1, C, 0, 0, 0);
    const int i = (jt - 32) * 2 + (c >> 3);
#pragma unroll
    for (int r = 0; r < 4; r++) {
      float wvv = C[r] + bias;
      mx[r] += s_v[w][quad * 4 + r][3 * i] * wvv;
      my[r] += s_v[w][quad * 4 + r][3 * i + 1] * wvv;
      mz[r] += s_v[w][quad * 4 + r][3 * i + 2] * wvv;
    }
  }

  // fold the two column-halves (c and c^8 share output j = c&7)
#pragma unroll
  for (int r = 0; r < 4; r++) {
    t3[r] += __shfl_xor(t3[r], 8);
    mx[r] += __shfl_xor(mx[r], 8);
    my[r] += __shfl_xor(my[r], 8);
    mz[r] += __shfl_xor(mz[r], 8);
  }

  // ---- epilogue: scale + atomic scatter ----
#pragma unroll
  for (int r = 0; r < 4; r++) {
    const int e = quad * 4 + r;
    float ew = s_ew[w][e];
    float sc = A_PATH * ew;
    int dst = s_dst[w][e];
    float sh0 = s_sh[w][e][0];
    atomicAdd(&agg0[(long long)dst * 16 + c], (sh0 * p1[r] + p2[r]) * sc);
    if (c < 8) {
      float t3v = t3[r] * sc;
      float scs = sc * sh0;
      float ox = t3v * s_sh[w][e][1] + mx[r] * scs;
      float oy = t3v * s_sh[w][e][2] + my[r] * scs;
      float oz = t3v * s_sh[w][e][3] + mz[r] * scs;
      long long b = (long long)dst * 24 + (long long)c * 3;
      atomicAdd(&agg1[b], ox);
      atomicAdd(&agg1[b + 1], oy);
      atomicAdd(&agg1[b + 2], oz);
    } else if (c == 8) {
      atomicAdd(&normb[dst], ew);
    }
  }
}

// ---------------- final node kernel (vectorized loads/stores) ----------------
extern "C" __global__ __launch_bounds__(256) void k_node(
    const float* __restrict__ x, const float* __restrict__ xnorm,
    const float* __restrict__ agg0, const float* __restrict__ agg1,
    const float* __restrict__ normb, const float* __restrict__ Wm_s,
    const float* __restrict__ Wm_v, const float* __restrict__ Wu_s,
    const float* __restrict__ Wu_v, const float* __restrict__ Ws_s,
    const float* __restrict__ Ws_v, const float* __restrict__ res_scale_p,
    float* __restrict__ out, int N) {
  __shared__ float sWms[384];
  __shared__ float sWmv[64];
  __shared__ float sWus[256];
  __shared__ float sWuv[64];
  __shared__ float sWss[256];
  __shared__ float sWsv[64];
  int t = threadIdx.x;
  for (int i = t; i < 384; i += 256) sWms[i] = Wm_s[i];
  if (t < 64) sWmv[t] = Wm_v[t];
  sWus[t] = Wu_s[t];
  if (t < 64) sWuv[t] = Wu_v[t];
  sWss[t] = Ws_s[t];
  if (t < 64) sWsv[t] = Ws_v[t];
  __syncthreads();
  int n = blockIdx.x * 256 + t;
  if (n >= N) return;

  float inv = 1.0f / fmaxf(normb[n], EPSF);
  float4 a04[4], a14[6];
  {
    const float4* p = (const float4*)(agg0 + (long long)n * 16);
#pragma unroll
    for (int i = 0; i < 4; i++) a04[i] = p[i];
    const float4* q = (const float4*)(agg1 + (long long)n * 24);
#pragma unroll
    for (int i = 0; i < 6; i++) a14[i] = q[i];
  }
  float* a0 = (float*)a04;
  float* a1 = (float*)a14;
#pragma unroll
  for (int i = 0; i < 16; i++) a0[i] *= inv;
#pragma unroll
  for (int i = 0; i < 24; i++) a1[i] *= inv;

  float scal[16], gate[8];
#pragma unroll
  for (int jj = 0; jj < 24; jj++) {
    float acc = 0.f;
#pragma unroll
    for (int i = 0; i < 16; i++) acc += a0[i] * sWms[i * 24 + jj];
    acc *= Q16;
    if (jj < 16) scal[jj] = acc * sigm(acc);
    else gate[jj - 16] = sigm(acc);
  }
  float vg[24];
#pragma unroll
  for (int j = 0; j < 8; j++) {
    float g = gate[j];
#pragma unroll
    for (int cc = 0; cc < 3; cc++) {
      float acc = 0.f;
#pragma unroll
      for (int i = 0; i < 8; i++) acc += a1[i * 3 + cc] * sWmv[i * 8 + j];
      vg[j * 3 + cc] = acc * Q8 * g;
    }
  }
  float4 xn4[10], xo4[10];
  {
    const float4* p = (const float4*)(xnorm + (long long)n * 40);
    const float4* q = (const float4*)(x + (long long)n * 40);
#pragma unroll
    for (int i = 0; i < 10; i++) { xn4[i] = p[i]; xo4[i] = q[i]; }
  }
  const float* xn = (const float*)xn4;
  const float* xo = (const float*)xo4;
  float rs = res_scale_p[0];

  float4 ob[10];
  float* ov = (float*)ob;
#pragma unroll
  for (int j = 0; j < 16; j++) {
    float acc = 0.f, acc2 = 0.f;
#pragma unroll
    for (int i = 0; i < 16; i++) {
      acc += scal[i] * sWus[i * 16 + j];
      acc2 += xn[i] * sWss[i * 16 + j];
    }
    ov[j] = xo[j] + rs * ((acc + acc2) * Q16);
  }
#pragma unroll
  for (int j = 0; j < 8; j++) {
#pragma unroll
    for (int cc = 0; cc < 3; cc++) {
      float acc = 0.f;
#pragma unroll
      for (int i = 0; i < 8; i++)
        acc += vg[i * 3 + cc] * sWuv[i * 8 + j] + xn[16 + i * 3 + cc] * sWsv[i * 8 + j];
      ov[16 + j * 3 + cc] = xo[16 + j * 3 + cc] + rs * (acc * Q8);
    }
  }
  float4* po = (float4*)(out + (long long)n * 40);
#pragma unroll
  for (int i = 0; i < 10; i++) po[i] = ob[i];
}

// ---------------- launch ----------------
extern "C" void kernel_launch(void* const* d_in, const int* in_sizes, int n_in,
                              void* d_out, int out_size, void* d_ws, size_t ws_size,
                              hipStream_t stream) {
  const float* x = (const float*)d_in[0];
  const int* esrc = (const int*)d_in[1];
  const int* edst = (const int*)d_in[2];
  const float* sh = (const float*)d_in[3];
  const float* rbf = (const float*)d_in[4];
  const float* elen = (const float*)d_in[5];
  const float* w_r1 = (const float*)d_in[6];
  const float* b_r1 = (const float*)d_in[7];
  const float* w_r2 = (const float*)d_in[8];
  const float* b_r2 = (const float*)d_in[9];
  const float* w_g1 = (const float*)d_in[10];
  const float* b_g1 = (const float*)d_in[11];
  const float* w_g2 = (const float*)d_in[12];
  const float* b_g2 = (const float*)d_in[13];
  const float* Wm_s = (const float*)d_in[14];
  const float* Wm_v = (const float*)d_in[15];
  const float* Wu_s = (const float*)d_in[16];
  const float* Wu_v = (const float*)d_in[17];
  const float* Ws_s = (const float*)d_in[18];
  const float* Ws_v = (const float*)d_in[19];
  const float* res_scale = (const float*)d_in[20];

  const int N = in_sizes[0] / 40;
  const int E = in_sizes[1];

  char* ws = (char*)d_ws;
  size_t off = 0;
  float* xnorm = (float*)(ws + off); off += (size_t)N * 40 * sizeof(float);
  off = (off + 255) & ~(size_t)255;
  float* agg0 = (float*)(ws + off); off += (size_t)N * 16 * sizeof(float);
  float* agg1 = (float*)(ws + off); off += (size_t)N * 24 * sizeof(float);
  float* normb = (float*)(ws + off); off += (size_t)N * sizeof(float);
  off = (off + 255) & ~(size_t)255;
  f16* W2T = (f16*)(ws + off); off += (size_t)WNUM * 64 * sizeof(f16);

  // zero accumulators (agg0, agg1, normb are contiguous)
  hipMemsetAsync(agg0, 0, (size_t)N * 41 * sizeof(float), stream);

  k_prep_w2t<<<(HID * WNUM + 255) / 256, 256, 0, stream>>>(w_r2, W2T);
  k_xnorm<<<(N + 255) / 256, 256, 0, stream>>>(x, xnorm, N);

  int nblk = (E + 63) / 64;
  k_edge<<<nblk, 256, 0, stream>>>(xnorm, esrc, edst, sh, rbf, elen, w_r1, b_r1,
                                   w_g1, b_g1, w_g2, b_g2, b_r2, W2T, agg0, agg1,
                                   normb, E);

  k_node<<<(N + 255) / 256, 256, 0, stream>>>(x, xnorm, agg0, agg1, normb, Wm_s,
                                              Wm_v, Wu_s, Wu_v, Ws_s, Ws_v,
                                              res_scale, (float*)d_out, N);
}